// Round 18
// baseline (145.931 us; speedup 1.0000x reference)
//
#include <hip/hip_runtime.h>
#include <hip/hip_fp16.h>

// out = segment_sum(adj_val * x[adj_src], adj_dst) @ W  +  x @ Wr
// z = x@W (bf16 MFMA) stored row-scaled INT8; residual x@Wr stored BF16;
// CSR-by-dst gather writes out fresh (init from bf16 residual).
// Pipeline (6 dispatches): memset(ccnt) -> {hist | wprep} -> scanc ->
// {gemm | binsort1} grid-fused with EXACT 1:1 INTERLEAVE (even->gemm,
// odd->binsort, id=b>>1; r17's %3 striping mis-assumed grid=3*NB1 and left
// 131 sort chunks unprocessed) -> binsort2 -> gather (~6TB/s roofline).

typedef __attribute__((ext_vector_type(8))) short bf16x8;
typedef __attribute__((ext_vector_type(4))) float f32x4;

#define BSH 8          // coarse bucket = dst >> 8  (256 nodes per bucket)
#define CHUNK 4096     // edges per block in hist/binsort1
#define K2 18          // reg-held edges per thread in binsort2

__device__ __forceinline__ unsigned short f2b(float f) {   // f32 -> bf16 RNE
    unsigned u = __float_as_uint(f);
    return (unsigned short)((u + 0x7FFFu + ((u >> 16) & 1u)) >> 16);
}

// ---- fused: coarse histogram (blocks < histBlocks) | weight prep (rest) --
__global__ __launch_bounds__(512) void prep_hist(const float* __restrict__ W,
                                                 const float* __restrict__ Wr,
                                                 unsigned short* __restrict__ Wt,
                                                 unsigned short* __restrict__ Wrt,
                                                 const int* __restrict__ dst,
                                                 int* __restrict__ ccnt,
                                                 int E, int NBK, int histBlocks) {
    __shared__ int lh[512];
    if ((int)blockIdx.x < histBlocks) {
        for (int i = threadIdx.x; i < NBK; i += 512) lh[i] = 0;
        __syncthreads();
        const int base = blockIdx.x * CHUNK;
        #pragma unroll
        for (int i = 0; i < CHUNK / 512; ++i) {
            int e = base + i * 512 + threadIdx.x;
            if (e < E) atomicAdd(&lh[dst[e] >> BSH], 1);
        }
        __syncthreads();
        for (int i = threadIdx.x; i < NBK; i += 512)
            if (lh[i]) atomicAdd(&ccnt[i], lh[i]);
        return;
    }
    int gid = ((int)blockIdx.x - histBlocks) * 512 + threadIdx.x;
    if (gid < 16384) {                 // 128x128 weight transpose -> bf16
        int k = gid >> 7, n = gid & 127;
        Wt[(n << 7) + k]  = f2b(W[gid]);
        Wrt[(n << 7) + k] = f2b(Wr[gid]);
    }
}

// ---- coarse exclusive scan: single block of 512, NBK <= 512 --------------
__global__ __launch_bounds__(512) void scanc(const int* __restrict__ ccnt,
                                             int* __restrict__ coff,
                                             int* __restrict__ ccur, int NBK) {
    __shared__ int sh2[512];
    const int t = threadIdx.x;
    int c = (t < NBK) ? ccnt[t] : 0;
    sh2[t] = c;
    __syncthreads();
    #pragma unroll
    for (int d = 1; d < 512; d <<= 1) {
        int v = (t >= d) ? sh2[t - d] : 0;
        __syncthreads();
        sh2[t] += v;
        __syncthreads();
    }
    int ex = sh2[t] - c;
    if (t < NBK) { coff[t] = ex; ccur[t] = ex; }
}

// ---- fused: MFMA GEMM | binsort1, exact 1:1 interleave -------------------
// b < 2*min(G,B): odd -> binsort, even -> gemm, id = b>>1.
// b >= 2*min(G,B): tail belongs to the larger role.
__global__ __launch_bounds__(512) void gemm_bin(const float* __restrict__ x,
                                                const unsigned short* __restrict__ Wt,
                                                const unsigned short* __restrict__ Wrt,
                                                unsigned* __restrict__ z8u,
                                                float* __restrict__ rowscale,
                                                unsigned* __restrict__ res16,
                                                int N,
                                                const float* __restrict__ val,
                                                const int* __restrict__ src,
                                                const int* __restrict__ dst,
                                                int* __restrict__ ccur,
                                                uint2* __restrict__ epk1,
                                                int E, int NBK,
                                                int gemmBlocks, int NB1) {
    __shared__ uint4 lw[4096];   // 64 KB: gemm weights | binsort1 lh/lbase

    const int b = (int)blockIdx.x;
    const int M = min(gemmBlocks, NB1);
    bool isBin;
    int id;
    if (b < 2 * M) {
        isBin = (b & 1);
        id = b >> 1;
    } else {
        isBin = (NB1 > gemmBlocks);
        id = M + (b - 2 * M);
    }

    if (isBin) {
        // ---- binsort1 part: coarse bin, single uint2 random write stream --
        int* lh = (int*)lw;
        int* lbase = lh + 512;
        for (int i = threadIdx.x; i < NBK; i += 512) lh[i] = 0;
        __syncthreads();
        const int base = id * CHUNK;
        int rank[CHUNK / 512];
        int bk[CHUNK / 512];
        #pragma unroll
        for (int i = 0; i < CHUNK / 512; ++i) {
            int e = base + i * 512 + threadIdx.x;
            if (e < E) {
                int bkt = dst[e] >> BSH;
                bk[i] = bkt;
                rank[i] = atomicAdd(&lh[bkt], 1);
            } else bk[i] = -1;
        }
        __syncthreads();
        for (int i = threadIdx.x; i < NBK; i += 512)
            lbase[i] = lh[i] ? atomicAdd(&ccur[i], lh[i]) : 0;
        __syncthreads();
        #pragma unroll
        for (int i = 0; i < CHUNK / 512; ++i) {
            int e = base + i * 512 + threadIdx.x;
            if (e >= E) break;
            int p = lbase[bk[i]] + rank[i];
            __half hv = __float2half(val[e]);
            unsigned short hu;
            __builtin_memcpy(&hu, &hv, 2);
            epk1[p] = make_uint2((unsigned)src[e] | ((unsigned)(hu & 0x7FFFu) << 17),
                                 (unsigned)dst[e]);
        }
        return;
    }

    // ---- GEMM part ----
    const int gemmId = id;
    const int tid = threadIdx.x;
    const int wave = tid >> 6;
    const int lane = tid & 63;
    const int l15 = lane & 15;
    const int lhi = lane >> 4;

    const uint4* wtg = reinterpret_cast<const uint4*>(Wt);
    const uint4* wrg = reinterpret_cast<const uint4*>(Wrt);
    #pragma unroll
    for (int it = 0; it < 4; ++it) {
        int c = it * 512 + tid;
        int row = c >> 4, cc = c & 15;
        int sc = cc ^ (row & 7);
        lw[row * 16 + sc] = wtg[c];
        lw[2048 + row * 16 + sc] = wrg[c];
    }
    __syncthreads();

    const int rowBase = gemmId * 256 + wave * 32;
    const int r0 = rowBase + l15;
    const int r1 = rowBase + 16 + l15;
    const size_t xo0 = (size_t)(r0 < N ? r0 : N - 1) * 128;
    const size_t xo1 = (size_t)(r1 < N ? r1 : N - 1) * 128;

    f32x4 accW[8][2], accR[8][2];
    #pragma unroll
    for (int fn = 0; fn < 8; ++fn) {
        accW[fn][0] = (f32x4)0.f; accW[fn][1] = (f32x4)0.f;
        accR[fn][0] = (f32x4)0.f; accR[fn][1] = (f32x4)0.f;
    }

    #pragma unroll
    for (int ks = 0; ks < 4; ++ks) {
        const int kb = ks * 32 + lhi * 8;
        float4 a0 = *reinterpret_cast<const float4*>(&x[xo0 + kb]);
        float4 b0 = *reinterpret_cast<const float4*>(&x[xo0 + kb + 4]);
        float4 a1 = *reinterpret_cast<const float4*>(&x[xo1 + kb]);
        float4 b1 = *reinterpret_cast<const float4*>(&x[xo1 + kb + 4]);
        union { bf16x8 v; unsigned u[4]; } xf0, xf1;
        xf0.u[0] = (unsigned)f2b(a0.x) | ((unsigned)f2b(a0.y) << 16);
        xf0.u[1] = (unsigned)f2b(a0.z) | ((unsigned)f2b(a0.w) << 16);
        xf0.u[2] = (unsigned)f2b(b0.x) | ((unsigned)f2b(b0.y) << 16);
        xf0.u[3] = (unsigned)f2b(b0.z) | ((unsigned)f2b(b0.w) << 16);
        xf1.u[0] = (unsigned)f2b(a1.x) | ((unsigned)f2b(a1.y) << 16);
        xf1.u[1] = (unsigned)f2b(a1.z) | ((unsigned)f2b(a1.w) << 16);
        xf1.u[2] = (unsigned)f2b(b1.x) | ((unsigned)f2b(b1.y) << 16);
        xf1.u[3] = (unsigned)f2b(b1.z) | ((unsigned)f2b(b1.w) << 16);

        const int sl = ks * 4 + lhi;
        #pragma unroll
        for (int fn = 0; fn < 8; ++fn) {
            int wrow = fn * 16 + l15;
            int idx = wrow * 16 + (sl ^ (wrow & 7));
            bf16x8 wf  = *reinterpret_cast<const bf16x8*>(&lw[idx]);
            bf16x8 wrf = *reinterpret_cast<const bf16x8*>(&lw[2048 + idx]);
            accW[fn][0] = __builtin_amdgcn_mfma_f32_16x16x32_bf16(wf,  xf0.v, accW[fn][0], 0, 0, 0);
            accW[fn][1] = __builtin_amdgcn_mfma_f32_16x16x32_bf16(wf,  xf1.v, accW[fn][1], 0, 0, 0);
            accR[fn][0] = __builtin_amdgcn_mfma_f32_16x16x32_bf16(wrf, xf0.v, accR[fn][0], 0, 0, 0);
            accR[fn][1] = __builtin_amdgcn_mfma_f32_16x16x32_bf16(wrf, xf1.v, accR[fn][1], 0, 0, 0);
        }
    }

    #pragma unroll
    for (int fr = 0; fr < 2; ++fr) {
        int row = rowBase + fr * 16 + l15;
        float m = 0.f;
        #pragma unroll
        for (int fn = 0; fn < 8; ++fn)
            #pragma unroll
            for (int j = 0; j < 4; ++j)
                m = fmaxf(m, fabsf(accW[fn][fr][j]));
        m = fmaxf(m, __shfl_xor(m, 16));
        m = fmaxf(m, __shfl_xor(m, 32));
        m = fmaxf(m, 1e-20f);
        const float qs = 127.0f / m;

        if (row >= N) continue;
        if (lhi == 0) rowscale[row] = m * (1.0f / 127.0f);
        #pragma unroll
        for (int fn = 0; fn < 8; ++fn) {
            int c = fn * 16 + lhi * 4;
            uint2 pr;
            pr.x = (unsigned)f2b(accR[fn][fr][0]) | ((unsigned)f2b(accR[fn][fr][1]) << 16);
            pr.y = (unsigned)f2b(accR[fn][fr][2]) | ((unsigned)f2b(accR[fn][fr][3]) << 16);
            *reinterpret_cast<uint2*>(&res16[(size_t)row * 64 + (c >> 1)]) = pr;
            int q0 = (int)rintf(accW[fn][fr][0] * qs);
            int q1 = (int)rintf(accW[fn][fr][1] * qs);
            int q2 = (int)rintf(accW[fn][fr][2] * qs);
            int q3 = (int)rintf(accW[fn][fr][3] * qs);
            unsigned pq = (unsigned)(q0 & 255) | ((unsigned)(q1 & 255) << 8) |
                          ((unsigned)(q2 & 255) << 16) | ((unsigned)(q3 & 255) << 24);
            z8u[(size_t)row * 32 + fn * 4 + lhi] = pq;
        }
    }
}

__device__ __forceinline__ float h15f(unsigned h) {
    unsigned short u = (unsigned short)(h & 0x7FFFu);
    __half hv;
    __builtin_memcpy(&hv, &u, 2);
    return __half2float(hv);
}

// ---- pass 2 (r12-proven): fine sort + per-node off/cnt; rowscale premult -
__global__ __launch_bounds__(256) void binsort2(const uint2* __restrict__ epk1,
                                                const int* __restrict__ coff,
                                                const int* __restrict__ ccnt,
                                                const float* __restrict__ rowscale,
                                                unsigned* __restrict__ epk,
                                                int* __restrict__ off,
                                                int* __restrict__ cnt, int N) {
    __shared__ int lcnt[256];
    __shared__ int sh[256];
    __shared__ int lcur[256];
    const int b = blockIdx.x;
    const int s = coff[b];
    const int n = ccnt[b];
    const int t = threadIdx.x;
    const int gnode = (b << BSH) + t;

    lcnt[t] = 0;
    __syncthreads();

    uint2 q[K2];
    #pragma unroll
    for (int r = 0; r < K2; ++r) {
        int i = t + r * 256;
        if (i < n) {
            q[r] = epk1[s + i];
            atomicAdd(&lcnt[q[r].y & 255], 1);
        }
    }
    for (int i = t + K2 * 256; i < n; i += 256)          // rare overflow tail
        atomicAdd(&lcnt[epk1[s + i].y & 255], 1);
    __syncthreads();

    int c = lcnt[t];
    sh[t] = c;
    __syncthreads();
    #pragma unroll
    for (int d = 1; d < 256; d <<= 1) {
        int v = (t >= d) ? sh[t - d] : 0;
        __syncthreads();
        sh[t] += v;
        __syncthreads();
    }
    int ex = sh[t] - c;
    lcur[t] = ex;
    if (gnode < N) {
        off[gnode] = s + ex;
        cnt[gnode] = c;
    }
    __syncthreads();

    #pragma unroll
    for (int r = 0; r < K2; ++r) {
        int i = t + r * 256;
        if (i < n) {
            unsigned srcv = q[r].x & 0x1FFFFu;
            float v = h15f(q[r].x >> 17) * rowscale[srcv];
            int p = s + atomicAdd(&lcur[q[r].y & 255], 1);
            epk[p] = (srcv << 15) | ((unsigned)f2b(v) & 0x7FFFu);
        }
    }
    for (int i = t + K2 * 256; i < n; i += 256) {        // rare overflow tail
        uint2 v2 = epk1[s + i];
        unsigned srcv = v2.x & 0x1FFFFu;
        float v = h15f(v2.x >> 17) * rowscale[srcv];
        int p = s + atomicAdd(&lcur[v2.y & 255], 1);
        epk[p] = (srcv << 15) | ((unsigned)f2b(v) & 0x7FFFu);
    }
}

// ---- gather: one wave per node; s_load edge stream; 8 z-loads in flight --
// acc init from bf16 residual; out written fresh (never read).
__global__ __launch_bounds__(256) void spmm_gather(const unsigned short* __restrict__ z8u,
                                                   const unsigned* __restrict__ res16,
                                                   const unsigned* __restrict__ epk,
                                                   const int* __restrict__ off,
                                                   const int* __restrict__ cnt,
                                                   float* __restrict__ out, int N) {
    const int lane = threadIdx.x & 63;
    const int node = (int)((blockIdx.x * (size_t)blockDim.x + threadIdx.x) >> 6);
    if (node >= N) return;
    const int base = __builtin_amdgcn_readfirstlane(off[node]);
    const int deg  = __builtin_amdgcn_readfirstlane(cnt[node]);
    const unsigned* __restrict__ ep = epk + base;

    unsigned r0i = res16[(size_t)node * 64 + lane];
    float2 acc;
    acc.x = __uint_as_float(r0i << 16);
    acc.y = __uint_as_float(r0i & 0xFFFF0000u);

    int j = 0;
    for (; j + 8 <= deg; j += 8) {
        unsigned p0 = ep[j + 0], p1 = ep[j + 1], p2 = ep[j + 2], p3 = ep[j + 3];
        unsigned p4 = ep[j + 4], p5 = ep[j + 5], p6 = ep[j + 6], p7 = ep[j + 7];
        unsigned short w0 = z8u[(size_t)(p0 >> 15) * 64 + lane];
        unsigned short w1 = z8u[(size_t)(p1 >> 15) * 64 + lane];
        unsigned short w2 = z8u[(size_t)(p2 >> 15) * 64 + lane];
        unsigned short w3 = z8u[(size_t)(p3 >> 15) * 64 + lane];
        unsigned short w4 = z8u[(size_t)(p4 >> 15) * 64 + lane];
        unsigned short w5 = z8u[(size_t)(p5 >> 15) * 64 + lane];
        unsigned short w6 = z8u[(size_t)(p6 >> 15) * 64 + lane];
        unsigned short w7 = z8u[(size_t)(p7 >> 15) * 64 + lane];
        float v0 = __uint_as_float((p0 & 0x7FFFu) << 16);
        float v1 = __uint_as_float((p1 & 0x7FFFu) << 16);
        float v2 = __uint_as_float((p2 & 0x7FFFu) << 16);
        float v3 = __uint_as_float((p3 & 0x7FFFu) << 16);
        float v4 = __uint_as_float((p4 & 0x7FFFu) << 16);
        float v5 = __uint_as_float((p5 & 0x7FFFu) << 16);
        float v6 = __uint_as_float((p6 & 0x7FFFu) << 16);
        float v7 = __uint_as_float((p7 & 0x7FFFu) << 16);
        acc.x = fmaf(v0, (float)(signed char)(w0 & 0xFF), acc.x);
        acc.y = fmaf(v0, (float)(signed char)(w0 >> 8), acc.y);
        acc.x = fmaf(v1, (float)(signed char)(w1 & 0xFF), acc.x);
        acc.y = fmaf(v1, (float)(signed char)(w1 >> 8), acc.y);
        acc.x = fmaf(v2, (float)(signed char)(w2 & 0xFF), acc.x);
        acc.y = fmaf(v2, (float)(signed char)(w2 >> 8), acc.y);
        acc.x = fmaf(v3, (float)(signed char)(w3 & 0xFF), acc.x);
        acc.y = fmaf(v3, (float)(signed char)(w3 >> 8), acc.y);
        acc.x = fmaf(v4, (float)(signed char)(w4 & 0xFF), acc.x);
        acc.y = fmaf(v4, (float)(signed char)(w4 >> 8), acc.y);
        acc.x = fmaf(v5, (float)(signed char)(w5 & 0xFF), acc.x);
        acc.y = fmaf(v5, (float)(signed char)(w5 >> 8), acc.y);
        acc.x = fmaf(v6, (float)(signed char)(w6 & 0xFF), acc.x);
        acc.y = fmaf(v6, (float)(signed char)(w6 >> 8), acc.y);
        acc.x = fmaf(v7, (float)(signed char)(w7 & 0xFF), acc.x);
        acc.y = fmaf(v7, (float)(signed char)(w7 >> 8), acc.y);
    }
    for (; j < deg; ++j) {
        unsigned p = ep[j];
        unsigned short wv = z8u[(size_t)(p >> 15) * 64 + lane];
        float v = __uint_as_float((p & 0x7FFFu) << 16);
        acc.x = fmaf(v, (float)(signed char)(wv & 0xFF), acc.x);
        acc.y = fmaf(v, (float)(signed char)(wv >> 8), acc.y);
    }
    *reinterpret_cast<float2*>(&out[(size_t)node * 128 + lane * 2]) = acc;
}

extern "C" void kernel_launch(void* const* d_in, const int* in_sizes, int n_in,
                              void* d_out, int out_size, void* d_ws, size_t ws_size,
                              hipStream_t stream) {
    const float* x    = (const float*)d_in[0];
    // d_in[1] = h0 (unused, variant=False)
    const float* aval = (const float*)d_in[2];
    const float* W    = (const float*)d_in[3];
    const float* Wr   = (const float*)d_in[4];
    const int*   asrc = (const int*)d_in[5];
    const int*   adst = (const int*)d_in[6];
    float* out = (float*)d_out;

    const int nx = in_sizes[0];
    const int N = nx / 128;
    const int E = in_sizes[2];
    const int NBK = (N + (1 << BSH) - 1) >> BSH;          // 391 coarse buckets
    const int NB1 = (E + CHUNK - 1) / CHUNK;              // 391 edge blocks
    const int gemmBlocks = (N + 255) / 256;               // 391
    const int wprepBlocks = (16384 + 511) / 512;

    // workspace layout
    char* w = (char*)d_ws;
    uint2* epk1 = (uint2*)w;                  w += (size_t)E * 8;    // 12.8 MB
    unsigned* z8 = (unsigned*)w;              w += (size_t)nx;       // 12.8 MB int8 z
    unsigned* res16 = (unsigned*)w;           w += (size_t)nx * 2;   // 25.6 MB bf16 residual
    float* rowscale = (float*)w;              w += (size_t)N * 4;
    unsigned short* Wt = (unsigned short*)w;  w += 16384 * 2;
    unsigned short* Wrt= (unsigned short*)w;  w += 16384 * 2;
    int* off    = (int*)w;  w += (size_t)N * 4;
    int* cnt    = (int*)w;  w += (size_t)N * 4;
    int* ccnt   = (int*)w;  w += 2048;
    int* coff   = (int*)w;  w += 2048;
    int* ccur   = (int*)w;  w += 2048;
    unsigned* epk = (unsigned*)w;  w += (size_t)E * 4;               // 6.4 MB

    hipMemsetAsync(ccnt, 0, (size_t)NBK * 4, stream);
    prep_hist<<<NB1 + wprepBlocks, 512, 0, stream>>>(W, Wr, Wt, Wrt, adst, ccnt, E, NBK, NB1);
    scanc<<<1, 512, 0, stream>>>(ccnt, coff, ccur, NBK);
    gemm_bin<<<gemmBlocks + NB1, 512, 0, stream>>>(x, Wt, Wrt, z8, rowscale, res16, N,
                                                   aval, asrc, adst, ccur, epk1,
                                                   E, NBK, gemmBlocks, NB1);
    binsort2<<<NBK, 256, 0, stream>>>(epk1, coff, ccnt, rowscale, epk, off, cnt, N);
    spmm_gather<<<(int)(((size_t)N * 64 + 255) / 256), 256, 0, stream>>>(
        (const unsigned short*)z8, res16, epk, off, cnt, out, N);
}

// Round 19
// 135.724 us; speedup vs baseline: 1.0752x; 1.0752x over previous
//
#include <hip/hip_runtime.h>
#include <hip/hip_fp16.h>

// out = segment_sum(adj_val * x[adj_src], adj_dst) @ W  +  x @ Wr
// z = x@W (bf16 MFMA) stored row-scaled INT8; residual x@Wr stored BF16;
// CSR-by-dst gather writes out fresh (init from bf16 residual).
// Pipeline (6 dispatches): memset(ccnt) -> {hist | wprep} -> scanc ->
// {gemm | binsort1} grid-fused IN-ORDER (r16-proven 137.1us; r18's 1:1
// striping regressed to 145.9 - in-order keeps gemm blocks' x-reads L2-local
// and lets binsort ride the gemm tail) -> binsort2 -> gather (~6TB/s roofline).
// gemm occupancy is VGPR-locked (108 -> 4 waves/SIMD); setprio(1) wraps the
// MFMA cluster (T5: pays when co-resident waves have different roles).

typedef __attribute__((ext_vector_type(8))) short bf16x8;
typedef __attribute__((ext_vector_type(4))) float f32x4;

#define BSH 8          // coarse bucket = dst >> 8  (256 nodes per bucket)
#define CHUNK 4096     // edges per block in hist/binsort1
#define K2 18          // reg-held edges per thread in binsort2

__device__ __forceinline__ unsigned short f2b(float f) {   // f32 -> bf16 RNE
    unsigned u = __float_as_uint(f);
    return (unsigned short)((u + 0x7FFFu + ((u >> 16) & 1u)) >> 16);
}

// ---- fused: coarse histogram (blocks < histBlocks) | weight prep (rest) --
__global__ __launch_bounds__(512) void prep_hist(const float* __restrict__ W,
                                                 const float* __restrict__ Wr,
                                                 unsigned short* __restrict__ Wt,
                                                 unsigned short* __restrict__ Wrt,
                                                 const int* __restrict__ dst,
                                                 int* __restrict__ ccnt,
                                                 int E, int NBK, int histBlocks) {
    __shared__ int lh[512];
    if ((int)blockIdx.x < histBlocks) {
        for (int i = threadIdx.x; i < NBK; i += 512) lh[i] = 0;
        __syncthreads();
        const int base = blockIdx.x * CHUNK;
        #pragma unroll
        for (int i = 0; i < CHUNK / 512; ++i) {
            int e = base + i * 512 + threadIdx.x;
            if (e < E) atomicAdd(&lh[dst[e] >> BSH], 1);
        }
        __syncthreads();
        for (int i = threadIdx.x; i < NBK; i += 512)
            if (lh[i]) atomicAdd(&ccnt[i], lh[i]);
        return;
    }
    int gid = ((int)blockIdx.x - histBlocks) * 512 + threadIdx.x;
    if (gid < 16384) {                 // 128x128 weight transpose -> bf16
        int k = gid >> 7, n = gid & 127;
        Wt[(n << 7) + k]  = f2b(W[gid]);
        Wrt[(n << 7) + k] = f2b(Wr[gid]);
    }
}

// ---- coarse exclusive scan: single block of 512, NBK <= 512 --------------
__global__ __launch_bounds__(512) void scanc(const int* __restrict__ ccnt,
                                             int* __restrict__ coff,
                                             int* __restrict__ ccur, int NBK) {
    __shared__ int sh2[512];
    const int t = threadIdx.x;
    int c = (t < NBK) ? ccnt[t] : 0;
    sh2[t] = c;
    __syncthreads();
    #pragma unroll
    for (int d = 1; d < 512; d <<= 1) {
        int v = (t >= d) ? sh2[t - d] : 0;
        __syncthreads();
        sh2[t] += v;
        __syncthreads();
    }
    int ex = sh2[t] - c;
    if (t < NBK) { coff[t] = ex; ccur[t] = ex; }
}

// ---- fused: MFMA GEMM (blocks < gemmBlocks) | binsort1 (rest) ------------
// GEMM writes z8 (row-scaled int8) and res16 (bf16 residual x@Wr).
__global__ __launch_bounds__(512) void gemm_bin(const float* __restrict__ x,
                                                const unsigned short* __restrict__ Wt,
                                                const unsigned short* __restrict__ Wrt,
                                                unsigned* __restrict__ z8u,
                                                float* __restrict__ rowscale,
                                                unsigned* __restrict__ res16,
                                                int N,
                                                const float* __restrict__ val,
                                                const int* __restrict__ src,
                                                const int* __restrict__ dst,
                                                int* __restrict__ ccur,
                                                uint2* __restrict__ epk1,
                                                int E, int NBK, int gemmBlocks) {
    __shared__ uint4 lw[4096];   // 64 KB: gemm weights | binsort1 lh/lbase

    if ((int)blockIdx.x >= gemmBlocks) {
        // ---- binsort1 part: coarse bin, single uint2 random write stream --
        int* lh = (int*)lw;
        int* lbase = lh + 512;
        const int bb = (int)blockIdx.x - gemmBlocks;
        for (int i = threadIdx.x; i < NBK; i += 512) lh[i] = 0;
        __syncthreads();
        const int base = bb * CHUNK;
        int rank[CHUNK / 512];
        int bk[CHUNK / 512];
        #pragma unroll
        for (int i = 0; i < CHUNK / 512; ++i) {
            int e = base + i * 512 + threadIdx.x;
            if (e < E) {
                int bkt = dst[e] >> BSH;
                bk[i] = bkt;
                rank[i] = atomicAdd(&lh[bkt], 1);
            } else bk[i] = -1;
        }
        __syncthreads();
        for (int i = threadIdx.x; i < NBK; i += 512)
            lbase[i] = lh[i] ? atomicAdd(&ccur[i], lh[i]) : 0;
        __syncthreads();
        #pragma unroll
        for (int i = 0; i < CHUNK / 512; ++i) {
            int e = base + i * 512 + threadIdx.x;
            if (e >= E) break;
            int p = lbase[bk[i]] + rank[i];
            __half hv = __float2half(val[e]);
            unsigned short hu;
            __builtin_memcpy(&hu, &hv, 2);
            epk1[p] = make_uint2((unsigned)src[e] | ((unsigned)(hu & 0x7FFFu) << 17),
                                 (unsigned)dst[e]);
        }
        return;
    }

    // ---- GEMM part ----
    const int tid = threadIdx.x;
    const int wave = tid >> 6;
    const int lane = tid & 63;
    const int l15 = lane & 15;
    const int lhi = lane >> 4;

    const uint4* wtg = reinterpret_cast<const uint4*>(Wt);
    const uint4* wrg = reinterpret_cast<const uint4*>(Wrt);
    #pragma unroll
    for (int it = 0; it < 4; ++it) {
        int c = it * 512 + tid;
        int row = c >> 4, cc = c & 15;
        int sc = cc ^ (row & 7);
        lw[row * 16 + sc] = wtg[c];
        lw[2048 + row * 16 + sc] = wrg[c];
    }
    __syncthreads();

    const int rowBase = blockIdx.x * 256 + wave * 32;
    const int r0 = rowBase + l15;
    const int r1 = rowBase + 16 + l15;
    const size_t xo0 = (size_t)(r0 < N ? r0 : N - 1) * 128;
    const size_t xo1 = (size_t)(r1 < N ? r1 : N - 1) * 128;

    f32x4 accW[8][2], accR[8][2];
    #pragma unroll
    for (int fn = 0; fn < 8; ++fn) {
        accW[fn][0] = (f32x4)0.f; accW[fn][1] = (f32x4)0.f;
        accR[fn][0] = (f32x4)0.f; accR[fn][1] = (f32x4)0.f;
    }

    #pragma unroll
    for (int ks = 0; ks < 4; ++ks) {
        const int kb = ks * 32 + lhi * 8;
        float4 a0 = *reinterpret_cast<const float4*>(&x[xo0 + kb]);
        float4 b0 = *reinterpret_cast<const float4*>(&x[xo0 + kb + 4]);
        float4 a1 = *reinterpret_cast<const float4*>(&x[xo1 + kb]);
        float4 b1 = *reinterpret_cast<const float4*>(&x[xo1 + kb + 4]);
        union { bf16x8 v; unsigned u[4]; } xf0, xf1;
        xf0.u[0] = (unsigned)f2b(a0.x) | ((unsigned)f2b(a0.y) << 16);
        xf0.u[1] = (unsigned)f2b(a0.z) | ((unsigned)f2b(a0.w) << 16);
        xf0.u[2] = (unsigned)f2b(b0.x) | ((unsigned)f2b(b0.y) << 16);
        xf0.u[3] = (unsigned)f2b(b0.z) | ((unsigned)f2b(b0.w) << 16);
        xf1.u[0] = (unsigned)f2b(a1.x) | ((unsigned)f2b(a1.y) << 16);
        xf1.u[1] = (unsigned)f2b(a1.z) | ((unsigned)f2b(a1.w) << 16);
        xf1.u[2] = (unsigned)f2b(b1.x) | ((unsigned)f2b(b1.y) << 16);
        xf1.u[3] = (unsigned)f2b(b1.z) | ((unsigned)f2b(b1.w) << 16);

        const int sl = ks * 4 + lhi;
        __builtin_amdgcn_s_setprio(1);
        #pragma unroll
        for (int fn = 0; fn < 8; ++fn) {
            int wrow = fn * 16 + l15;
            int idx = wrow * 16 + (sl ^ (wrow & 7));
            bf16x8 wf  = *reinterpret_cast<const bf16x8*>(&lw[idx]);
            bf16x8 wrf = *reinterpret_cast<const bf16x8*>(&lw[2048 + idx]);
            accW[fn][0] = __builtin_amdgcn_mfma_f32_16x16x32_bf16(wf,  xf0.v, accW[fn][0], 0, 0, 0);
            accW[fn][1] = __builtin_amdgcn_mfma_f32_16x16x32_bf16(wf,  xf1.v, accW[fn][1], 0, 0, 0);
            accR[fn][0] = __builtin_amdgcn_mfma_f32_16x16x32_bf16(wrf, xf0.v, accR[fn][0], 0, 0, 0);
            accR[fn][1] = __builtin_amdgcn_mfma_f32_16x16x32_bf16(wrf, xf1.v, accR[fn][1], 0, 0, 0);
        }
        __builtin_amdgcn_s_setprio(0);
    }

    #pragma unroll
    for (int fr = 0; fr < 2; ++fr) {
        int row = rowBase + fr * 16 + l15;
        float m = 0.f;
        #pragma unroll
        for (int fn = 0; fn < 8; ++fn)
            #pragma unroll
            for (int j = 0; j < 4; ++j)
                m = fmaxf(m, fabsf(accW[fn][fr][j]));
        m = fmaxf(m, __shfl_xor(m, 16));
        m = fmaxf(m, __shfl_xor(m, 32));
        m = fmaxf(m, 1e-20f);
        const float qs = 127.0f / m;

        if (row >= N) continue;
        if (lhi == 0) rowscale[row] = m * (1.0f / 127.0f);
        #pragma unroll
        for (int fn = 0; fn < 8; ++fn) {
            int c = fn * 16 + lhi * 4;
            uint2 pr;
            pr.x = (unsigned)f2b(accR[fn][fr][0]) | ((unsigned)f2b(accR[fn][fr][1]) << 16);
            pr.y = (unsigned)f2b(accR[fn][fr][2]) | ((unsigned)f2b(accR[fn][fr][3]) << 16);
            *reinterpret_cast<uint2*>(&res16[(size_t)row * 64 + (c >> 1)]) = pr;
            int q0 = (int)rintf(accW[fn][fr][0] * qs);
            int q1 = (int)rintf(accW[fn][fr][1] * qs);
            int q2 = (int)rintf(accW[fn][fr][2] * qs);
            int q3 = (int)rintf(accW[fn][fr][3] * qs);
            unsigned pq = (unsigned)(q0 & 255) | ((unsigned)(q1 & 255) << 8) |
                          ((unsigned)(q2 & 255) << 16) | ((unsigned)(q3 & 255) << 24);
            z8u[(size_t)row * 32 + fn * 4 + lhi] = pq;
        }
    }
}

__device__ __forceinline__ float h15f(unsigned h) {
    unsigned short u = (unsigned short)(h & 0x7FFFu);
    __half hv;
    __builtin_memcpy(&hv, &u, 2);
    return __half2float(hv);
}

// ---- pass 2 (r12-proven): fine sort + per-node off/cnt; rowscale premult -
__global__ __launch_bounds__(256) void binsort2(const uint2* __restrict__ epk1,
                                                const int* __restrict__ coff,
                                                const int* __restrict__ ccnt,
                                                const float* __restrict__ rowscale,
                                                unsigned* __restrict__ epk,
                                                int* __restrict__ off,
                                                int* __restrict__ cnt, int N) {
    __shared__ int lcnt[256];
    __shared__ int sh[256];
    __shared__ int lcur[256];
    const int b = blockIdx.x;
    const int s = coff[b];
    const int n = ccnt[b];
    const int t = threadIdx.x;
    const int gnode = (b << BSH) + t;

    lcnt[t] = 0;
    __syncthreads();

    uint2 q[K2];
    #pragma unroll
    for (int r = 0; r < K2; ++r) {
        int i = t + r * 256;
        if (i < n) {
            q[r] = epk1[s + i];
            atomicAdd(&lcnt[q[r].y & 255], 1);
        }
    }
    for (int i = t + K2 * 256; i < n; i += 256)          // rare overflow tail
        atomicAdd(&lcnt[epk1[s + i].y & 255], 1);
    __syncthreads();

    int c = lcnt[t];
    sh[t] = c;
    __syncthreads();
    #pragma unroll
    for (int d = 1; d < 256; d <<= 1) {
        int v = (t >= d) ? sh[t - d] : 0;
        __syncthreads();
        sh[t] += v;
        __syncthreads();
    }
    int ex = sh[t] - c;
    lcur[t] = ex;
    if (gnode < N) {
        off[gnode] = s + ex;
        cnt[gnode] = c;
    }
    __syncthreads();

    #pragma unroll
    for (int r = 0; r < K2; ++r) {
        int i = t + r * 256;
        if (i < n) {
            unsigned srcv = q[r].x & 0x1FFFFu;
            float v = h15f(q[r].x >> 17) * rowscale[srcv];
            int p = s + atomicAdd(&lcur[q[r].y & 255], 1);
            epk[p] = (srcv << 15) | ((unsigned)f2b(v) & 0x7FFFu);
        }
    }
    for (int i = t + K2 * 256; i < n; i += 256) {        // rare overflow tail
        uint2 v2 = epk1[s + i];
        unsigned srcv = v2.x & 0x1FFFFu;
        float v = h15f(v2.x >> 17) * rowscale[srcv];
        int p = s + atomicAdd(&lcur[v2.y & 255], 1);
        epk[p] = (srcv << 15) | ((unsigned)f2b(v) & 0x7FFFu);
    }
}

// ---- gather: one wave per node; s_load edge stream; 8 z-loads in flight --
// acc init from bf16 residual; out written fresh (never read).
__global__ __launch_bounds__(256) void spmm_gather(const unsigned short* __restrict__ z8u,
                                                   const unsigned* __restrict__ res16,
                                                   const unsigned* __restrict__ epk,
                                                   const int* __restrict__ off,
                                                   const int* __restrict__ cnt,
                                                   float* __restrict__ out, int N) {
    const int lane = threadIdx.x & 63;
    const int node = (int)((blockIdx.x * (size_t)blockDim.x + threadIdx.x) >> 6);
    if (node >= N) return;
    const int base = __builtin_amdgcn_readfirstlane(off[node]);
    const int deg  = __builtin_amdgcn_readfirstlane(cnt[node]);
    const unsigned* __restrict__ ep = epk + base;

    unsigned r0i = res16[(size_t)node * 64 + lane];
    float2 acc;
    acc.x = __uint_as_float(r0i << 16);
    acc.y = __uint_as_float(r0i & 0xFFFF0000u);

    int j = 0;
    for (; j + 8 <= deg; j += 8) {
        unsigned p0 = ep[j + 0], p1 = ep[j + 1], p2 = ep[j + 2], p3 = ep[j + 3];
        unsigned p4 = ep[j + 4], p5 = ep[j + 5], p6 = ep[j + 6], p7 = ep[j + 7];
        unsigned short w0 = z8u[(size_t)(p0 >> 15) * 64 + lane];
        unsigned short w1 = z8u[(size_t)(p1 >> 15) * 64 + lane];
        unsigned short w2 = z8u[(size_t)(p2 >> 15) * 64 + lane];
        unsigned short w3 = z8u[(size_t)(p3 >> 15) * 64 + lane];
        unsigned short w4 = z8u[(size_t)(p4 >> 15) * 64 + lane];
        unsigned short w5 = z8u[(size_t)(p5 >> 15) * 64 + lane];
        unsigned short w6 = z8u[(size_t)(p6 >> 15) * 64 + lane];
        unsigned short w7 = z8u[(size_t)(p7 >> 15) * 64 + lane];
        float v0 = __uint_as_float((p0 & 0x7FFFu) << 16);
        float v1 = __uint_as_float((p1 & 0x7FFFu) << 16);
        float v2 = __uint_as_float((p2 & 0x7FFFu) << 16);
        float v3 = __uint_as_float((p3 & 0x7FFFu) << 16);
        float v4 = __uint_as_float((p4 & 0x7FFFu) << 16);
        float v5 = __uint_as_float((p5 & 0x7FFFu) << 16);
        float v6 = __uint_as_float((p6 & 0x7FFFu) << 16);
        float v7 = __uint_as_float((p7 & 0x7FFFu) << 16);
        acc.x = fmaf(v0, (float)(signed char)(w0 & 0xFF), acc.x);
        acc.y = fmaf(v0, (float)(signed char)(w0 >> 8), acc.y);
        acc.x = fmaf(v1, (float)(signed char)(w1 & 0xFF), acc.x);
        acc.y = fmaf(v1, (float)(signed char)(w1 >> 8), acc.y);
        acc.x = fmaf(v2, (float)(signed char)(w2 & 0xFF), acc.x);
        acc.y = fmaf(v2, (float)(signed char)(w2 >> 8), acc.y);
        acc.x = fmaf(v3, (float)(signed char)(w3 & 0xFF), acc.x);
        acc.y = fmaf(v3, (float)(signed char)(w3 >> 8), acc.y);
        acc.x = fmaf(v4, (float)(signed char)(w4 & 0xFF), acc.x);
        acc.y = fmaf(v4, (float)(signed char)(w4 >> 8), acc.y);
        acc.x = fmaf(v5, (float)(signed char)(w5 & 0xFF), acc.x);
        acc.y = fmaf(v5, (float)(signed char)(w5 >> 8), acc.y);
        acc.x = fmaf(v6, (float)(signed char)(w6 & 0xFF), acc.x);
        acc.y = fmaf(v6, (float)(signed char)(w6 >> 8), acc.y);
        acc.x = fmaf(v7, (float)(signed char)(w7 & 0xFF), acc.x);
        acc.y = fmaf(v7, (float)(signed char)(w7 >> 8), acc.y);
    }
    for (; j < deg; ++j) {
        unsigned p = ep[j];
        unsigned short wv = z8u[(size_t)(p >> 15) * 64 + lane];
        float v = __uint_as_float((p & 0x7FFFu) << 16);
        acc.x = fmaf(v, (float)(signed char)(wv & 0xFF), acc.x);
        acc.y = fmaf(v, (float)(signed char)(wv >> 8), acc.y);
    }
    *reinterpret_cast<float2*>(&out[(size_t)node * 128 + lane * 2]) = acc;
}

extern "C" void kernel_launch(void* const* d_in, const int* in_sizes, int n_in,
                              void* d_out, int out_size, void* d_ws, size_t ws_size,
                              hipStream_t stream) {
    const float* x    = (const float*)d_in[0];
    // d_in[1] = h0 (unused, variant=False)
    const float* aval = (const float*)d_in[2];
    const float* W    = (const float*)d_in[3];
    const float* Wr   = (const float*)d_in[4];
    const int*   asrc = (const int*)d_in[5];
    const int*   adst = (const int*)d_in[6];
    float* out = (float*)d_out;

    const int nx = in_sizes[0];
    const int N = nx / 128;
    const int E = in_sizes[2];
    const int NBK = (N + (1 << BSH) - 1) >> BSH;          // 391 coarse buckets
    const int NB1 = (E + CHUNK - 1) / CHUNK;              // 391 edge blocks
    const int gemmBlocks = (N + 255) / 256;               // 391
    const int wprepBlocks = (16384 + 511) / 512;

    // workspace layout
    char* w = (char*)d_ws;
    uint2* epk1 = (uint2*)w;                  w += (size_t)E * 8;    // 12.8 MB
    unsigned* z8 = (unsigned*)w;              w += (size_t)nx;       // 12.8 MB int8 z
    unsigned* res16 = (unsigned*)w;           w += (size_t)nx * 2;   // 25.6 MB bf16 residual
    float* rowscale = (float*)w;              w += (size_t)N * 4;
    unsigned short* Wt = (unsigned short*)w;  w += 16384 * 2;
    unsigned short* Wrt= (unsigned short*)w;  w += 16384 * 2;
    int* off    = (int*)w;  w += (size_t)N * 4;
    int* cnt    = (int*)w;  w += (size_t)N * 4;
    int* ccnt   = (int*)w;  w += 2048;
    int* coff   = (int*)w;  w += 2048;
    int* ccur   = (int*)w;  w += 2048;
    unsigned* epk = (unsigned*)w;  w += (size_t)E * 4;               // 6.4 MB

    hipMemsetAsync(ccnt, 0, (size_t)NBK * 4, stream);
    prep_hist<<<NB1 + wprepBlocks, 512, 0, stream>>>(W, Wr, Wt, Wrt, adst, ccnt, E, NBK, NB1);
    scanc<<<1, 512, 0, stream>>>(ccnt, coff, ccur, NBK);
    gemm_bin<<<gemmBlocks + NB1, 512, 0, stream>>>(x, Wt, Wrt, z8, rowscale, res16, N,
                                                   aval, asrc, adst, ccur, epk1,
                                                   E, NBK, gemmBlocks);
    binsort2<<<NBK, 256, 0, stream>>>(epk1, coff, ccnt, rowscale, epk, off, cnt, N);
    spmm_gather<<<(int)(((size_t)N * 64 + 255) / 256), 256, 0, stream>>>(
        (const unsigned short*)z8, res16, epk, off, cnt, out, N);
}

// Round 20
// 134.917 us; speedup vs baseline: 1.0816x; 1.0060x over previous
//
#include <hip/hip_runtime.h>
#include <hip/hip_fp16.h>

// out = segment_sum(adj_val * x[adj_src], adj_dst) @ W  +  x @ Wr
// z = x@W (bf16 MFMA) stored row-scaled INT8; residual x@Wr stored BF16;
// CSR-by-dst gather writes out fresh (init from bf16 residual).
// Pipeline (6 dispatches): memset(ccnt) -> {hist | wprep} -> scanc ->
// {gemmA | gemmB | binsort1} one in-order dispatch: r19's single gemm block
// computed BOTH products -> 128 acc VGPRs + 64KB LDS locked occupancy at
// 4 waves/SIMD (latency-bound, MfmaUtil 3.5%). Splitting A=x@W, B=x@Wr per
// block halves both (32KB LDS, ~half acc regs) -> higher occupancy; x read
// twice (cheap at 18% HBM). In-order role layout (r18: striping regressed).
// -> binsort2 (rowscale premult) -> gather (~6TB/s mixed-traffic roofline).

typedef __attribute__((ext_vector_type(8))) short bf16x8;
typedef __attribute__((ext_vector_type(4))) float f32x4;

#define BSH 8          // coarse bucket = dst >> 8  (256 nodes per bucket)
#define CHUNK 4096     // edges per block in hist/binsort1
#define K2 18          // reg-held edges per thread in binsort2

__device__ __forceinline__ unsigned short f2b(float f) {   // f32 -> bf16 RNE
    unsigned u = __float_as_uint(f);
    return (unsigned short)((u + 0x7FFFu + ((u >> 16) & 1u)) >> 16);
}

// ---- fused: coarse histogram (blocks < histBlocks) | weight prep (rest) --
__global__ __launch_bounds__(512) void prep_hist(const float* __restrict__ W,
                                                 const float* __restrict__ Wr,
                                                 unsigned short* __restrict__ Wt,
                                                 unsigned short* __restrict__ Wrt,
                                                 const int* __restrict__ dst,
                                                 int* __restrict__ ccnt,
                                                 int E, int NBK, int histBlocks) {
    __shared__ int lh[512];
    if ((int)blockIdx.x < histBlocks) {
        for (int i = threadIdx.x; i < NBK; i += 512) lh[i] = 0;
        __syncthreads();
        const int base = blockIdx.x * CHUNK;
        #pragma unroll
        for (int i = 0; i < CHUNK / 512; ++i) {
            int e = base + i * 512 + threadIdx.x;
            if (e < E) atomicAdd(&lh[dst[e] >> BSH], 1);
        }
        __syncthreads();
        for (int i = threadIdx.x; i < NBK; i += 512)
            if (lh[i]) atomicAdd(&ccnt[i], lh[i]);
        return;
    }
    int gid = ((int)blockIdx.x - histBlocks) * 512 + threadIdx.x;
    if (gid < 16384) {                 // 128x128 weight transpose -> bf16
        int k = gid >> 7, n = gid & 127;
        Wt[(n << 7) + k]  = f2b(W[gid]);
        Wrt[(n << 7) + k] = f2b(Wr[gid]);
    }
}

// ---- coarse exclusive scan: single block of 512, NBK <= 512 --------------
__global__ __launch_bounds__(512) void scanc(const int* __restrict__ ccnt,
                                             int* __restrict__ coff,
                                             int* __restrict__ ccur, int NBK) {
    __shared__ int sh2[512];
    const int t = threadIdx.x;
    int c = (t < NBK) ? ccnt[t] : 0;
    sh2[t] = c;
    __syncthreads();
    #pragma unroll
    for (int d = 1; d < 512; d <<= 1) {
        int v = (t >= d) ? sh2[t - d] : 0;
        __syncthreads();
        sh2[t] += v;
        __syncthreads();
    }
    int ex = sh2[t] - c;
    if (t < NBK) { coff[t] = ex; ccur[t] = ex; }
}

// ---- fused tri-role: gemmA (z8) | gemmB (res16) | binsort1 ---------------
// In-order: [0,G) = A, [G,2G) = B, [2G,2G+NB1) = binsort1. 32 KB LDS.
__global__ __launch_bounds__(512) void gemm_bin(const float* __restrict__ x,
                                                const unsigned short* __restrict__ Wt,
                                                const unsigned short* __restrict__ Wrt,
                                                unsigned* __restrict__ z8u,
                                                float* __restrict__ rowscale,
                                                unsigned* __restrict__ res16,
                                                int N,
                                                const float* __restrict__ val,
                                                const int* __restrict__ src,
                                                const int* __restrict__ dst,
                                                int* __restrict__ ccur,
                                                uint2* __restrict__ epk1,
                                                int E, int NBK, int G) {
    __shared__ uint4 lw[2048];   // 32 KB: one weight matrix | binsort1 lh/lbase

    const int b = (int)blockIdx.x;

    if (b >= 2 * G) {
        // ---- binsort1: coarse bin, single uint2 random write stream ----
        int* lh = (int*)lw;
        int* lbase = lh + 512;
        const int bb = b - 2 * G;
        for (int i = threadIdx.x; i < NBK; i += 512) lh[i] = 0;
        __syncthreads();
        const int base = bb * CHUNK;
        int rank[CHUNK / 512];
        int bk[CHUNK / 512];
        #pragma unroll
        for (int i = 0; i < CHUNK / 512; ++i) {
            int e = base + i * 512 + threadIdx.x;
            if (e < E) {
                int bkt = dst[e] >> BSH;
                bk[i] = bkt;
                rank[i] = atomicAdd(&lh[bkt], 1);
            } else bk[i] = -1;
        }
        __syncthreads();
        for (int i = threadIdx.x; i < NBK; i += 512)
            lbase[i] = lh[i] ? atomicAdd(&ccur[i], lh[i]) : 0;
        __syncthreads();
        #pragma unroll
        for (int i = 0; i < CHUNK / 512; ++i) {
            int e = base + i * 512 + threadIdx.x;
            if (e >= E) break;
            int p = lbase[bk[i]] + rank[i];
            __half hv = __float2half(val[e]);
            unsigned short hu;
            __builtin_memcpy(&hu, &hv, 2);
            epk1[p] = make_uint2((unsigned)src[e] | ((unsigned)(hu & 0x7FFFu) << 17),
                                 (unsigned)dst[e]);
        }
        return;
    }

    const bool isA = (b < G);
    const int gemmId = isA ? b : (b - G);
    const int tid = threadIdx.x;
    const int wave = tid >> 6;
    const int lane = tid & 63;
    const int l15 = lane & 15;
    const int lhi = lane >> 4;

    // stage one weight matrix (32 KB, swizzled)
    const uint4* wg = reinterpret_cast<const uint4*>(isA ? Wt : Wrt);
    #pragma unroll
    for (int it = 0; it < 4; ++it) {
        int c = it * 512 + tid;
        int row = c >> 4, cc = c & 15;
        int sc = cc ^ (row & 7);
        lw[row * 16 + sc] = wg[c];
    }
    __syncthreads();

    const int rowBase = gemmId * 256 + wave * 32;
    const int r0 = rowBase + l15;
    const int r1 = rowBase + 16 + l15;
    const size_t xo0 = (size_t)(r0 < N ? r0 : N - 1) * 128;
    const size_t xo1 = (size_t)(r1 < N ? r1 : N - 1) * 128;

    f32x4 acc[8][2];
    #pragma unroll
    for (int fn = 0; fn < 8; ++fn) { acc[fn][0] = (f32x4)0.f; acc[fn][1] = (f32x4)0.f; }

    #pragma unroll
    for (int ks = 0; ks < 4; ++ks) {
        const int kb = ks * 32 + lhi * 8;
        float4 a0 = *reinterpret_cast<const float4*>(&x[xo0 + kb]);
        float4 b0 = *reinterpret_cast<const float4*>(&x[xo0 + kb + 4]);
        float4 a1 = *reinterpret_cast<const float4*>(&x[xo1 + kb]);
        float4 b1 = *reinterpret_cast<const float4*>(&x[xo1 + kb + 4]);
        union { bf16x8 v; unsigned u[4]; } xf0, xf1;
        xf0.u[0] = (unsigned)f2b(a0.x) | ((unsigned)f2b(a0.y) << 16);
        xf0.u[1] = (unsigned)f2b(a0.z) | ((unsigned)f2b(a0.w) << 16);
        xf0.u[2] = (unsigned)f2b(b0.x) | ((unsigned)f2b(b0.y) << 16);
        xf0.u[3] = (unsigned)f2b(b0.z) | ((unsigned)f2b(b0.w) << 16);
        xf1.u[0] = (unsigned)f2b(a1.x) | ((unsigned)f2b(a1.y) << 16);
        xf1.u[1] = (unsigned)f2b(a1.z) | ((unsigned)f2b(a1.w) << 16);
        xf1.u[2] = (unsigned)f2b(b1.x) | ((unsigned)f2b(b1.y) << 16);
        xf1.u[3] = (unsigned)f2b(b1.z) | ((unsigned)f2b(b1.w) << 16);

        const int sl = ks * 4 + lhi;
        __builtin_amdgcn_s_setprio(1);
        #pragma unroll
        for (int fn = 0; fn < 8; ++fn) {
            int wrow = fn * 16 + l15;
            int idx = wrow * 16 + (sl ^ (wrow & 7));
            bf16x8 wf = *reinterpret_cast<const bf16x8*>(&lw[idx]);
            acc[fn][0] = __builtin_amdgcn_mfma_f32_16x16x32_bf16(wf, xf0.v, acc[fn][0], 0, 0, 0);
            acc[fn][1] = __builtin_amdgcn_mfma_f32_16x16x32_bf16(wf, xf1.v, acc[fn][1], 0, 0, 0);
        }
        __builtin_amdgcn_s_setprio(0);
    }

    if (isA) {
        // epilogue A: per-row absmax -> rowscale + int8 z
        #pragma unroll
        for (int fr = 0; fr < 2; ++fr) {
            int row = rowBase + fr * 16 + l15;
            float m = 0.f;
            #pragma unroll
            for (int fn = 0; fn < 8; ++fn)
                #pragma unroll
                for (int j = 0; j < 4; ++j)
                    m = fmaxf(m, fabsf(acc[fn][fr][j]));
            m = fmaxf(m, __shfl_xor(m, 16));
            m = fmaxf(m, __shfl_xor(m, 32));
            m = fmaxf(m, 1e-20f);
            const float qs = 127.0f / m;

            if (row >= N) continue;
            if (lhi == 0) rowscale[row] = m * (1.0f / 127.0f);
            #pragma unroll
            for (int fn = 0; fn < 8; ++fn) {
                int q0 = (int)rintf(acc[fn][fr][0] * qs);
                int q1 = (int)rintf(acc[fn][fr][1] * qs);
                int q2 = (int)rintf(acc[fn][fr][2] * qs);
                int q3 = (int)rintf(acc[fn][fr][3] * qs);
                unsigned pq = (unsigned)(q0 & 255) | ((unsigned)(q1 & 255) << 8) |
                              ((unsigned)(q2 & 255) << 16) | ((unsigned)(q3 & 255) << 24);
                z8u[(size_t)row * 32 + fn * 4 + lhi] = pq;
            }
        }
    } else {
        // epilogue B: bf16 residual (no reduction needed)
        #pragma unroll
        for (int fr = 0; fr < 2; ++fr) {
            int row = rowBase + fr * 16 + l15;
            if (row >= N) continue;
            #pragma unroll
            for (int fn = 0; fn < 8; ++fn) {
                int c = fn * 16 + lhi * 4;
                uint2 pr;
                pr.x = (unsigned)f2b(acc[fn][fr][0]) | ((unsigned)f2b(acc[fn][fr][1]) << 16);
                pr.y = (unsigned)f2b(acc[fn][fr][2]) | ((unsigned)f2b(acc[fn][fr][3]) << 16);
                *reinterpret_cast<uint2*>(&res16[(size_t)row * 64 + (c >> 1)]) = pr;
            }
        }
    }
}

__device__ __forceinline__ float h15f(unsigned h) {
    unsigned short u = (unsigned short)(h & 0x7FFFu);
    __half hv;
    __builtin_memcpy(&hv, &u, 2);
    return __half2float(hv);
}

// ---- pass 2 (r12-proven): fine sort + per-node off/cnt; rowscale premult -
__global__ __launch_bounds__(256) void binsort2(const uint2* __restrict__ epk1,
                                                const int* __restrict__ coff,
                                                const int* __restrict__ ccnt,
                                                const float* __restrict__ rowscale,
                                                unsigned* __restrict__ epk,
                                                int* __restrict__ off,
                                                int* __restrict__ cnt, int N) {
    __shared__ int lcnt[256];
    __shared__ int sh[256];
    __shared__ int lcur[256];
    const int b = blockIdx.x;
    const int s = coff[b];
    const int n = ccnt[b];
    const int t = threadIdx.x;
    const int gnode = (b << BSH) + t;

    lcnt[t] = 0;
    __syncthreads();

    uint2 q[K2];
    #pragma unroll
    for (int r = 0; r < K2; ++r) {
        int i = t + r * 256;
        if (i < n) {
            q[r] = epk1[s + i];
            atomicAdd(&lcnt[q[r].y & 255], 1);
        }
    }
    for (int i = t + K2 * 256; i < n; i += 256)          // rare overflow tail
        atomicAdd(&lcnt[epk1[s + i].y & 255], 1);
    __syncthreads();

    int c = lcnt[t];
    sh[t] = c;
    __syncthreads();
    #pragma unroll
    for (int d = 1; d < 256; d <<= 1) {
        int v = (t >= d) ? sh[t - d] : 0;
        __syncthreads();
        sh[t] += v;
        __syncthreads();
    }
    int ex = sh[t] - c;
    lcur[t] = ex;
    if (gnode < N) {
        off[gnode] = s + ex;
        cnt[gnode] = c;
    }
    __syncthreads();

    #pragma unroll
    for (int r = 0; r < K2; ++r) {
        int i = t + r * 256;
        if (i < n) {
            unsigned srcv = q[r].x & 0x1FFFFu;
            float v = h15f(q[r].x >> 17) * rowscale[srcv];
            int p = s + atomicAdd(&lcur[q[r].y & 255], 1);
            epk[p] = (srcv << 15) | ((unsigned)f2b(v) & 0x7FFFu);
        }
    }
    for (int i = t + K2 * 256; i < n; i += 256) {        // rare overflow tail
        uint2 v2 = epk1[s + i];
        unsigned srcv = v2.x & 0x1FFFFu;
        float v = h15f(v2.x >> 17) * rowscale[srcv];
        int p = s + atomicAdd(&lcur[v2.y & 255], 1);
        epk[p] = (srcv << 15) | ((unsigned)f2b(v) & 0x7FFFu);
    }
}

// ---- gather: one wave per node; s_load edge stream; 8 z-loads in flight --
// acc init from bf16 residual; out written fresh (never read).
__global__ __launch_bounds__(256) void spmm_gather(const unsigned short* __restrict__ z8u,
                                                   const unsigned* __restrict__ res16,
                                                   const unsigned* __restrict__ epk,
                                                   const int* __restrict__ off,
                                                   const int* __restrict__ cnt,
                                                   float* __restrict__ out, int N) {
    const int lane = threadIdx.x & 63;
    const int node = (int)((blockIdx.x * (size_t)blockDim.x + threadIdx.x) >> 6);
    if (node >= N) return;
    const int base = __builtin_amdgcn_readfirstlane(off[node]);
    const int deg  = __builtin_amdgcn_readfirstlane(cnt[node]);
    const unsigned* __restrict__ ep = epk + base;

    unsigned r0i = res16[(size_t)node * 64 + lane];
    float2 acc;
    acc.x = __uint_as_float(r0i << 16);
    acc.y = __uint_as_float(r0i & 0xFFFF0000u);

    int j = 0;
    for (; j + 8 <= deg; j += 8) {
        unsigned p0 = ep[j + 0], p1 = ep[j + 1], p2 = ep[j + 2], p3 = ep[j + 3];
        unsigned p4 = ep[j + 4], p5 = ep[j + 5], p6 = ep[j + 6], p7 = ep[j + 7];
        unsigned short w0 = z8u[(size_t)(p0 >> 15) * 64 + lane];
        unsigned short w1 = z8u[(size_t)(p1 >> 15) * 64 + lane];
        unsigned short w2 = z8u[(size_t)(p2 >> 15) * 64 + lane];
        unsigned short w3 = z8u[(size_t)(p3 >> 15) * 64 + lane];
        unsigned short w4 = z8u[(size_t)(p4 >> 15) * 64 + lane];
        unsigned short w5 = z8u[(size_t)(p5 >> 15) * 64 + lane];
        unsigned short w6 = z8u[(size_t)(p6 >> 15) * 64 + lane];
        unsigned short w7 = z8u[(size_t)(p7 >> 15) * 64 + lane];
        float v0 = __uint_as_float((p0 & 0x7FFFu) << 16);
        float v1 = __uint_as_float((p1 & 0x7FFFu) << 16);
        float v2 = __uint_as_float((p2 & 0x7FFFu) << 16);
        float v3 = __uint_as_float((p3 & 0x7FFFu) << 16);
        float v4 = __uint_as_float((p4 & 0x7FFFu) << 16);
        float v5 = __uint_as_float((p5 & 0x7FFFu) << 16);
        float v6 = __uint_as_float((p6 & 0x7FFFu) << 16);
        float v7 = __uint_as_float((p7 & 0x7FFFu) << 16);
        acc.x = fmaf(v0, (float)(signed char)(w0 & 0xFF), acc.x);
        acc.y = fmaf(v0, (float)(signed char)(w0 >> 8), acc.y);
        acc.x = fmaf(v1, (float)(signed char)(w1 & 0xFF), acc.x);
        acc.y = fmaf(v1, (float)(signed char)(w1 >> 8), acc.y);
        acc.x = fmaf(v2, (float)(signed char)(w2 & 0xFF), acc.x);
        acc.y = fmaf(v2, (float)(signed char)(w2 >> 8), acc.y);
        acc.x = fmaf(v3, (float)(signed char)(w3 & 0xFF), acc.x);
        acc.y = fmaf(v3, (float)(signed char)(w3 >> 8), acc.y);
        acc.x = fmaf(v4, (float)(signed char)(w4 & 0xFF), acc.x);
        acc.y = fmaf(v4, (float)(signed char)(w4 >> 8), acc.y);
        acc.x = fmaf(v5, (float)(signed char)(w5 & 0xFF), acc.x);
        acc.y = fmaf(v5, (float)(signed char)(w5 >> 8), acc.y);
        acc.x = fmaf(v6, (float)(signed char)(w6 & 0xFF), acc.x);
        acc.y = fmaf(v6, (float)(signed char)(w6 >> 8), acc.y);
        acc.x = fmaf(v7, (float)(signed char)(w7 & 0xFF), acc.x);
        acc.y = fmaf(v7, (float)(signed char)(w7 >> 8), acc.y);
    }
    for (; j < deg; ++j) {
        unsigned p = ep[j];
        unsigned short wv = z8u[(size_t)(p >> 15) * 64 + lane];
        float v = __uint_as_float((p & 0x7FFFu) << 16);
        acc.x = fmaf(v, (float)(signed char)(wv & 0xFF), acc.x);
        acc.y = fmaf(v, (float)(signed char)(wv >> 8), acc.y);
    }
    *reinterpret_cast<float2*>(&out[(size_t)node * 128 + lane * 2]) = acc;
}

extern "C" void kernel_launch(void* const* d_in, const int* in_sizes, int n_in,
                              void* d_out, int out_size, void* d_ws, size_t ws_size,
                              hipStream_t stream) {
    const float* x    = (const float*)d_in[0];
    // d_in[1] = h0 (unused, variant=False)
    const float* aval = (const float*)d_in[2];
    const float* W    = (const float*)d_in[3];
    const float* Wr   = (const float*)d_in[4];
    const int*   asrc = (const int*)d_in[5];
    const int*   adst = (const int*)d_in[6];
    float* out = (float*)d_out;

    const int nx = in_sizes[0];
    const int N = nx / 128;
    const int E = in_sizes[2];
    const int NBK = (N + (1 << BSH) - 1) >> BSH;          // 391 coarse buckets
    const int NB1 = (E + CHUNK - 1) / CHUNK;              // 391 edge blocks
    const int G = (N + 255) / 256;                        // 391 gemm blocks/role
    const int wprepBlocks = (16384 + 511) / 512;

    // workspace layout
    char* w = (char*)d_ws;
    uint2* epk1 = (uint2*)w;                  w += (size_t)E * 8;    // 12.8 MB
    unsigned* z8 = (unsigned*)w;              w += (size_t)nx;       // 12.8 MB int8 z
    unsigned* res16 = (unsigned*)w;           w += (size_t)nx * 2;   // 25.6 MB bf16 residual
    float* rowscale = (float*)w;              w += (size_t)N * 4;
    unsigned short* Wt = (unsigned short*)w;  w += 16384 * 2;
    unsigned short* Wrt= (unsigned short*)w;  w += 16384 * 2;
    int* off    = (int*)w;  w += (size_t)N * 4;
    int* cnt    = (int*)w;  w += (size_t)N * 4;
    int* ccnt   = (int*)w;  w += 2048;
    int* coff   = (int*)w;  w += 2048;
    int* ccur   = (int*)w;  w += 2048;
    unsigned* epk = (unsigned*)w;  w += (size_t)E * 4;               // 6.4 MB

    hipMemsetAsync(ccnt, 0, (size_t)NBK * 4, stream);
    prep_hist<<<NB1 + wprepBlocks, 512, 0, stream>>>(W, Wr, Wt, Wrt, adst, ccnt, E, NBK, NB1);
    scanc<<<1, 512, 0, stream>>>(ccnt, coff, ccur, NBK);
    gemm_bin<<<2 * G + NB1, 512, 0, stream>>>(x, Wt, Wrt, z8, rowscale, res16, N,
                                              aval, asrc, adst, ccur, epk1,
                                              E, NBK, G);
    binsort2<<<NBK, 256, 0, stream>>>(epk1, coff, ccnt, rowscale, epk, off, cnt, N);
    spmm_gather<<<(int)(((size_t)N * 64 + 255) / 256), 256, 0, stream>>>(
        (const unsigned short*)z8, res16, epk, off, cnt, out, N);
}